// Round 8
// baseline (268.151 us; speedup 1.0000x reference)
//
#include <hip/hip_runtime.h>
#include <hip/hip_fp16.h>
#include <cstddef>
#include <cstdint>

// Problem constants (fixed by reference setup_inputs)
#define DMODEL 256
#define NHEAD  8
#define NLVL   4
#define NPT    4
#define DHEAD  32
#define DFFN   1024
#define SLEN   5440
#define BATCH  4
#define NTOK   (BATCH * SLEN)   // 21760 = 340*64 = 170*128
#define NT256  ((size_t)NTOK * 256)
#define GYR    170              // row-panels of 128 rows
#define GYP    176              // padded to multiple of 8 for XCD swizzle
#define LN_EPS 1e-5f

typedef __attribute__((ext_vector_type(4))) float f32x4;
typedef __attribute__((ext_vector_type(8))) short s16x8;

__device__ __forceinline__ unsigned short f2bf(float f) {
    union { float f; unsigned u; } v; v.f = f;
    unsigned u = v.u;
    u += 0x7FFFu + ((u >> 16) & 1u);   // round-to-nearest-even
    return (unsigned short)(u >> 16);
}
__device__ __forceinline__ float bf2f(unsigned short h) {
    union { unsigned u; float f; } v; v.u = ((unsigned)h) << 16;
    return v.f;
}

// async 16B global -> LDS (direct-to-shared, no VGPR round trip).
// lds dest must be wave-uniform base; HW writes lane l at base + l*16B.
__device__ __forceinline__ void g2l16(const unsigned short* g, unsigned short* l) {
    __builtin_amdgcn_global_load_lds(
        (const __attribute__((address_space(1))) unsigned int*)g,
        (__attribute__((address_space(3))) unsigned int*)l, 16, 0, 0);
}

// ---------------------------------------------------------------------------
// Fused prep + weight transposes (one launch).
// Blocks [0, 5440):   srcB = bf16(src); qB = bf16(src + pos)
// Blocks [5440, 5624): W [K][N] fp32 -> Wt [N][K] bf16 (all 6 weights;
//                      Woff & Wa into ONE concatenated WcatT [384][256]).
// ---------------------------------------------------------------------------
__global__ __launch_bounds__(256) void prep_tr_kernel(
    const float* __restrict__ src, const float* __restrict__ pos,
    unsigned short* __restrict__ srcB, unsigned short* __restrict__ qB,
    const float* __restrict__ Wv, const float* __restrict__ Woff,
    const float* __restrict__ Wa, const float* __restrict__ Wo,
    const float* __restrict__ W1, const float* __restrict__ W2,
    unsigned short* __restrict__ WvT, unsigned short* __restrict__ WcatT,
    unsigned short* __restrict__ WoT,
    unsigned short* __restrict__ W1T, unsigned short* __restrict__ W2T)
{
    if (blockIdx.x < 5440) {
        const size_t i = ((size_t)blockIdx.x * 256 + threadIdx.x) * 4;
        const float4 s = *(const float4*)(src + i);
        const float4 p = *(const float4*)(pos + i);
        ushort4 sb, qb;
        sb.x = f2bf(s.x); sb.y = f2bf(s.y); sb.z = f2bf(s.z); sb.w = f2bf(s.w);
        qb.x = f2bf(s.x + p.x); qb.y = f2bf(s.y + p.y);
        qb.z = f2bf(s.z + p.z); qb.w = f2bf(s.w + p.w);
        *(ushort4*)(srcB + i) = sb;
        *(ushort4*)(qB + i) = qb;
        return;
    }
    const int bid = blockIdx.x - 5440;
    const float* W; unsigned short* Wt; int K, N, t;
    if (bid < 16)       { W = Wv;   Wt = WvT;              K = 256;  N = 256;  t = bid; }
    else if (bid < 32)  { W = Woff; Wt = WcatT;            K = 256;  N = 256;  t = bid - 16; }
    else if (bid < 40)  { W = Wa;   Wt = WcatT + 256*256;  K = 256;  N = 128;  t = bid - 32; }
    else if (bid < 56)  { W = Wo;   Wt = WoT;              K = 256;  N = 256;  t = bid - 40; }
    else if (bid < 120) { W = W1;   Wt = W1T;              K = 256;  N = 1024; t = bid - 56; }
    else                { W = W2;   Wt = W2T;              K = 1024; N = 256;  t = bid - 120; }
    const int ntx = N >> 6;
    const int k0 = (t / ntx) * 64, n0 = (t % ntx) * 64;

    __shared__ float T[64][65];
    const int r  = threadIdx.x >> 4;
    const int c4 = (threadIdx.x & 15) * 4;
    #pragma unroll
    for (int rep = 0; rep < 4; rep++) {
        const int k = rep * 16 + r;
        const float4 v = *(const float4*)(W + (size_t)(k0 + k) * N + n0 + c4);
        T[c4 + 0][k] = v.x; T[c4 + 1][k] = v.y;
        T[c4 + 2][k] = v.z; T[c4 + 3][k] = v.w;
    }
    __syncthreads();
    #pragma unroll
    for (int rep = 0; rep < 4; rep++) {
        const int n = rep * 16 + r;
        ushort4 o;
        o.x = f2bf(T[n][c4 + 0]); o.y = f2bf(T[n][c4 + 1]);
        o.z = f2bf(T[n][c4 + 2]); o.w = f2bf(T[n][c4 + 3]);
        *(ushort4*)(Wt + (size_t)(n0 + n) * K + k0 + c4) = o;
    }
}

// ---------------------------------------------------------------------------
// 128x128 async-LDS GEMM with counted-vmcnt pipeline (round-5 validated).
// Used for value, olg, FFN1. Structure unchanged from round 5.
// ---------------------------------------------------------------------------
template <int KK, int NXB, bool RELU, int OM>
__global__ __launch_bounds__(256, 2) void gemm_lds_kernel(
    const unsigned short* __restrict__ A,
    const unsigned short* __restrict__ Bt,
    const float* __restrict__ bias, const float* __restrict__ bias2,
    int bsplit,
    void* __restrict__ Cout, int N)
{
    const int lin = blockIdx.x;
    const int c8  = lin & 7;
    const int rr  = lin >> 3;
    const int bx  = rr % NXB;
    const int yy  = (rr / NXB) * 8 + c8;
    if (yy >= GYR) return;              // uniform per block: safe before barrier
    const int row0 = yy * 128;
    const int col0 = bx * 128;

    __shared__ __align__(16) unsigned short sA[2][128 * 64];
    __shared__ __align__(16) unsigned short sB[2][128 * 64];

    const int tid  = threadIdx.x;
    const int wid  = tid >> 6;
    const int lane = tid & 63;
    const int m16  = lane & 15;
    const int q    = lane >> 4;
    const int wr   = (wid >> 1) * 64;    // wave's output row half
    const int wc   = (wid & 1) * 64;     // wave's output col half

    const int srow = lane >> 3;
    const int schk = (lane & 7) ^ srow;

    auto stage = [&](int buf, int kt) {   // 8 vmcnt ops per wave
        #pragma unroll
        for (int i = 0; i < 4; i++) {
            const int j = wid * 4 + i;           // 0..15 across the 4 waves
            const int r = j * 8 + srow;
            g2l16(A  + (size_t)(row0 + r) * KK + kt * 64 + schk * 8,
                  &sA[buf][j * 512]);
            g2l16(Bt + (size_t)(col0 + r) * KK + kt * 64 + schk * 8,
                  &sB[buf][j * 512]);
        }
    };

    f32x4 acc[4][4];
    #pragma unroll
    for (int m = 0; m < 4; m++)
        #pragma unroll
        for (int n = 0; n < 4; n++) acc[m][n] = (f32x4){0.f, 0.f, 0.f, 0.f};

    constexpr int NT = KK / 64;
    stage(0, 0);
    stage(1, 1);                         // 16 loads in flight

    #pragma unroll 1
    for (int kt = 0; kt < NT; kt++) {
        const int cur = kt & 1;

        if (kt + 1 < NT) asm volatile("s_waitcnt vmcnt(8)" ::: "memory");
        else             asm volatile("s_waitcnt vmcnt(0)" ::: "memory");
        __builtin_amdgcn_sched_barrier(0);
        __builtin_amdgcn_s_barrier();    // all waves' tile-kt loads done
        __builtin_amdgcn_sched_barrier(0);

        #pragma unroll
        for (int ks = 0; ks < 2; ks++) {
            s16x8 a[4], b[4];
            #pragma unroll
            for (int m = 0; m < 4; m++) {
                const int r  = wr + m * 16 + m16;
                const int cc = (ks * 4 + q) ^ (r & 7);   // un-swizzle on read
                a[m] = *(const s16x8*)&sA[cur][r * 64 + cc * 8];
            }
            #pragma unroll
            for (int n = 0; n < 4; n++) {
                const int r  = wc + n * 16 + m16;
                const int cc = (ks * 4 + q) ^ (r & 7);
                b[n] = *(const s16x8*)&sB[cur][r * 64 + cc * 8];
            }
            #pragma unroll
            for (int m = 0; m < 4; m++)
                #pragma unroll
                for (int n = 0; n < 4; n++)
                    acc[m][n] = __builtin_amdgcn_mfma_f32_16x16x32_bf16(
                        a[m], b[n], acc[m][n], 0, 0, 0);
        }

        asm volatile("s_waitcnt lgkmcnt(0)" ::: "memory");
        __builtin_amdgcn_sched_barrier(0);
        __builtin_amdgcn_s_barrier();
        __builtin_amdgcn_sched_barrier(0);

        if (kt + 2 < NT) stage(cur, kt + 2);   // same parity: kt+2 -> buf cur
    }

    #pragma unroll
    for (int n = 0; n < 4; n++) {
        const int col  = col0 + wc + n * 16 + m16;
        const float bc = (col < bsplit) ? bias[col] : bias2[col - bsplit];
        #pragma unroll
        for (int m = 0; m < 4; m++) {
            #pragma unroll
            for (int r = 0; r < 4; r++) {
                const int row = row0 + wr + m * 16 + q * 4 + r;
                float v = acc[m][n][r] + bc;
                if (RELU) v = fmaxf(v, 0.f);
                if (OM == 1)
                    ((unsigned short*)Cout)[(size_t)row * N + col] = f2bf(v);
                else if (OM == 2)
                    ((__half*)Cout)[(size_t)row * N + col] = __float2half(v);
                else
                    ((float*)Cout)[(size_t)row * N + col] = v;
            }
        }
    }
}

// ---------------------------------------------------------------------------
// WIDE N=256 GEMM with FUSED residual-add + LayerNorm epilogue.
// BM=128, BN=256, 4 waves (2x2, wave tile 64x128), counted-vmcnt dbuf loop
// (round-5 validated discipline). Each block owns COMPLETE output rows, so
// the LN over the 256-col row runs in-block: acc (+bias) -> fp32 LDS row
// buffer (stride 260 to break bank alias) in two 64-row passes; each wave
// LNs 16 rows/pass with the exact ln_kernel reduction order.
// Eliminates: the separate LN kernel AND the GEMM-result global round-trip.
// LNM=1 (Wo+LN1):  resid = fp32 src,  out = bf16 xB
// LNM=2 (FFN2+LN2): resid = bf16 xB,  out = fp32 final
// Grid = GYR = 170 blocks. LDS: staging 96KB; LN buffer (66KB) overlays it.
// NOTE: no pointer-array LDS bases (addrspacecast static-init is rejected
// on gfx950) — all buffers are computed offsets into one __shared__ array.
// ---------------------------------------------------------------------------
template <int KK, int LNM>
__global__ __launch_bounds__(256, 1) void gemm_wide_ln_kernel(
    const unsigned short* __restrict__ A,
    const unsigned short* __restrict__ Bt,
    const float* __restrict__ bias,
    const void* __restrict__ resid,
    const float* __restrict__ g, const float* __restrict__ be,
    void* __restrict__ outp)
{
    const int row0 = blockIdx.x * 128;

    // 96KB staging: sA at 0 (2x16KB halves), sB at 16384 (2x32KB halves).
    // LN buffer (fp32 [64][260], 66KB) aliases the same space after the loop.
    __shared__ __align__(16) unsigned short lds[49152];

    const int tid  = threadIdx.x;
    const int wid  = tid >> 6;
    const int lane = tid & 63;
    const int m16  = lane & 15;
    const int q    = lane >> 4;
    const int wr   = (wid >> 1) * 64;    // wave's output row half
    const int wc   = (wid & 1) * 128;    // wave's output col half

    const int srow = lane >> 3;
    const int schk = (lane & 7) ^ srow;

    auto stage = [&](int buf, int kt) {  // 12 vmcnt ops per wave (4 A + 8 B)
        unsigned short* sAb = lds + buf * 8192;            // 16KB halves
        unsigned short* sBb = lds + 16384 + buf * 16384;   // 32KB halves
        #pragma unroll
        for (int i = 0; i < 4; i++) {
            const int j = wid * 4 + i;       // 0..15
            const int r = j * 8 + srow;
            g2l16(A + (size_t)(row0 + r) * KK + kt * 64 + schk * 8,
                  sAb + j * 512);
        }
        #pragma unroll
        for (int i = 0; i < 8; i++) {
            const int j = wid * 8 + i;       // 0..31 -> B rows 0..255
            const int r = j * 8 + srow;
            g2l16(Bt + (size_t)r * KK + kt * 64 + schk * 8,
                  sBb + j * 512);
        }
    };

    f32x4 acc[4][8];
    #pragma unroll
    for (int m = 0; m < 4; m++)
        #pragma unroll
        for (int n = 0; n < 8; n++) acc[m][n] = (f32x4){0.f, 0.f, 0.f, 0.f};

    constexpr int NT = KK / 64;
    stage(0, 0);
    stage(1, 1);                         // 24 loads in flight

    #pragma unroll 1
    for (int kt = 0; kt < NT; kt++) {
        const int cur = kt & 1;
        const unsigned short* sAc = lds + cur * 8192;
        const unsigned short* sBc = lds + 16384 + cur * 16384;

        if (kt + 1 < NT) asm volatile("s_waitcnt vmcnt(12)" ::: "memory");
        else             asm volatile("s_waitcnt vmcnt(0)" ::: "memory");
        __builtin_amdgcn_sched_barrier(0);
        __builtin_amdgcn_s_barrier();
        __builtin_amdgcn_sched_barrier(0);

        #pragma unroll
        for (int ks = 0; ks < 2; ks++) {
            s16x8 a[4], b[8];
            #pragma unroll
            for (int m = 0; m < 4; m++) {
                const int r  = wr + m * 16 + m16;
                const int cc = (ks * 4 + q) ^ (r & 7);
                a[m] = *(const s16x8*)&sAc[r * 64 + cc * 8];
            }
            #pragma unroll
            for (int n = 0; n < 8; n++) {
                const int r  = wc + n * 16 + m16;
                const int cc = (ks * 4 + q) ^ (r & 7);
                b[n] = *(const s16x8*)&sBc[r * 64 + cc * 8];
            }
            #pragma unroll
            for (int m = 0; m < 4; m++)
                #pragma unroll
                for (int n = 0; n < 8; n++)
                    acc[m][n] = __builtin_amdgcn_mfma_f32_16x16x32_bf16(
                        a[m], b[n], acc[m][n], 0, 0, 0);
        }

        asm volatile("s_waitcnt lgkmcnt(0)" ::: "memory");
        __builtin_amdgcn_sched_barrier(0);
        __builtin_amdgcn_s_barrier();
        __builtin_amdgcn_sched_barrier(0);

        if (kt + 2 < NT) stage(cur, kt + 2);
    }
    // staging LDS now dead -> reuse as lnbuf
    float* lnbuf = (float*)lds;          // [64][260] fp32, 66KB

    // ---- fused residual + LN epilogue: two 64-row passes ----
    #pragma unroll 1
    for (int pass = 0; pass < 2; pass++) {
        if (wr == pass * 64) {           // waves owning these rows write acc
            #pragma unroll
            for (int n = 0; n < 8; n++) {
                const int col = wc + n * 16 + m16;
                const float bc = bias[col];
                #pragma unroll
                for (int m = 0; m < 4; m++)
                    #pragma unroll
                    for (int r = 0; r < 4; r++)
                        lnbuf[(m * 16 + q * 4 + r) * 260 + col] =
                            acc[m][n][r] + bc;
            }
        }
        __syncthreads();

        #pragma unroll 1
        for (int rr2 = 0; rr2 < 16; rr2++) {
            const int rl = wid * 16 + rr2;              // local row 0..63
            const size_t grow = (size_t)row0 + pass * 64 + rl;
            const size_t base = grow * 256 + lane * 4;

            float4 v = *(const float4*)&lnbuf[rl * 260 + lane * 4];
            if (LNM == 1) {
                const float4 rv = *(const float4*)((const float*)resid + base);
                v.x += rv.x; v.y += rv.y; v.z += rv.z; v.w += rv.w;
            } else {
                const ushort4 rb = *(const ushort4*)((const unsigned short*)resid + base);
                v.x += bf2f(rb.x); v.y += bf2f(rb.y);
                v.z += bf2f(rb.z); v.w += bf2f(rb.w);
            }

            float s  = v.x + v.y + v.z + v.w;
            float s2 = v.x * v.x + v.y * v.y + v.z * v.z + v.w * v.w;
            #pragma unroll
            for (int o = 32; o > 0; o >>= 1) {
                s  += __shfl_xor(s, o);
                s2 += __shfl_xor(s2, o);
            }
            const float mu  = s * (1.f / 256.f);
            const float var = s2 * (1.f / 256.f) - mu * mu;
            const float rn  = rsqrtf(var + LN_EPS);

            const float4 gv = *(const float4*)(g  + lane * 4);
            const float4 bv = *(const float4*)(be + lane * 4);
            float4 o4;
            o4.x = (v.x - mu) * rn * gv.x + bv.x;
            o4.y = (v.y - mu) * rn * gv.y + bv.y;
            o4.z = (v.z - mu) * rn * gv.z + bv.z;
            o4.w = (v.w - mu) * rn * gv.w + bv.w;
            if (LNM == 1) {
                ushort4 ob;
                ob.x = f2bf(o4.x); ob.y = f2bf(o4.y);
                ob.z = f2bf(o4.z); ob.w = f2bf(o4.w);
                *(ushort4*)((unsigned short*)outp + base) = ob;
            } else {
                *(float4*)((float*)outp + base) = o4;
            }
        }
        __syncthreads();                 // lnbuf reused by next pass
    }
}

// ---------------------------------------------------------------------------
// MSDA fused meta+gather: block = 8 tokens. (round-4 validated)
// ---------------------------------------------------------------------------
__global__ __launch_bounds__(256) void msda_sample_kernel(
    const __half* __restrict__ value, const float* __restrict__ olg,
    unsigned short* __restrict__ out)
{
    const int lin = blockIdx.x;          // 0..2719
    const int c8  = lin & 7;
    const int rr  = lin >> 3;            // 0..339
    const int b   = c8 >> 1;             // batch -> XCD pair
    const int i8  = (c8 & 1) + 2 * rr;   // 0..679: block within batch

    const int tid = threadIdx.x;
    const int sub = tid & 3;             // phase2: 16B channel group; phase1: pg
    const int h   = (tid >> 2) & 7;
    const int t8  = tid >> 5;
    const int q   = i8 * 8 + t8;         // token index within batch (< SLEN)
    const int bq  = b * SLEN + q;

    __shared__ __align__(16) uint4 smeta[8 * 16 * 8];   // [tok][p][h], 16KB

    // ---------------- phase 1: meta for (tok=t8, h, level=sub) -------------
    {
        int rem, Wq;
        if (q < 4096)      { rem = q;        Wq = 64; }
        else if (q < 5120) { rem = q - 4096; Wq = 32; }
        else if (q < 5376) { rem = q - 5120; Wq = 16; }
        else               { rem = q - 5376; Wq = 8;  }
        const int gy = rem / Wq;
        const int gx = rem - gy * Wq;
        const float ref_x = (gx + 0.5f) / (float)Wq;
        const float ref_y = (gy + 0.5f) / (float)Wq;

        const float4 lgv = *(const float4*)(olg + (size_t)bq * 384 + 256 + h * 16 + sub * 4);
        float mx = fmaxf(fmaxf(lgv.x, lgv.y), fmaxf(lgv.z, lgv.w));
        mx = fmaxf(mx, __shfl_xor(mx, 1));
        mx = fmaxf(mx, __shfl_xor(mx, 2));
        float e0 = expf(lgv.x - mx), e1 = expf(lgv.y - mx);
        float e2 = expf(lgv.z - mx), e3 = expf(lgv.w - mx);
        float s = e0 + e1 + e2 + e3;
        s += __shfl_xor(s, 1);
        s += __shfl_xor(s, 2);
        const float inv_s = 1.f / s;

        const float4 o01 = *(const float4*)(olg + (size_t)bq * 384 + h * 32 + sub * 8);
        const float4 o23 = *(const float4*)(olg + (size_t)bq * 384 + h * 32 + sub * 8 + 4);

        constexpr int LW[4] = {64, 32, 16, 8};
        constexpr int LS[4] = {0, 4096, 5120, 5376};
        const int Wl = LW[sub];
        const float fW = (float)Wl;
        const float ew[4] = {e0, e1, e2, e3};
        const float ox[4] = {o01.x, o01.z, o23.x, o23.z};
        const float oy[4] = {o01.y, o01.w, o23.y, o23.w};

        #pragma unroll
        for (int j = 0; j < 4; j++) {
            const float aw = ew[j] * inv_s;
            // mirror reference arithmetic exactly: (ref + off/W)*W - 0.5
            const float X = (ref_x + ox[j] / fW) * fW - 0.5f;
            const float Y = (ref_y + oy[j] / fW) * fW - 0.5f;
            const float x0f = floorf(X), y0f = floorf(Y);
            const float fx = X - x0f, fy = Y - y0f;
            const int x0 = (int)x0f, y0 = (int)y0f;

            unsigned idx[4]; __half hw[4];
            #pragma unroll
            for (int dy = 0; dy < 2; dy++) {
                const int yi = y0 + dy;
                const float wy = dy ? fy : (1.f - fy);
                const bool vy = (yi >= 0) && (yi < Wl);
                const int yc = min(max(yi, 0), Wl - 1);
                #pragma unroll
                for (int dx = 0; dx < 2; dx++) {
                    const int xi = x0 + dx;
                    const float wx = dx ? fx : (1.f - fx);
                    const bool vx = (xi >= 0) && (xi < Wl);
                    const int xc = min(max(xi, 0), Wl - 1);
                    const int c = dy * 2 + dx;
                    idx[c] = (unsigned)(LS[sub] + yc * Wl + xc);   // < 5440
                    hw[c] = __float2half((vx && vy) ? (aw * wx * wy) : 0.f);
                }
            }
            union { __half2 h2; unsigned u; } pk0, pk1;
            pk0.h2 = __halves2half2(hw[0], hw[1]);
            pk1.h2 = __halves2half2(hw[2], hw[3]);
            uint4 m;
            m.x = idx[0] | (idx[1] << 16);
            m.y = idx[2] | (idx[3] << 16);
            m.z = pk0.u;
            m.w = pk1.u;
            smeta[((t8 * 16) + sub * 4 + j) * 8 + h] = m;
        }
    }
    __syncthreads();

    // ---------------- phase 2: gather (validated structure) ----------------
    const char* vb = (const char*)value + (size_t)b * SLEN * 512;
    const unsigned laneoff = (unsigned)(h * 64 + sub * 16);
    const uint4* metap = &smeta[(t8 * 16) * 8 + h];    // index with p*8

    __half2 acc[4][4];
    #pragma unroll
    for (int i = 0; i < 4; i++)
        #pragma unroll
        for (int k = 0; k < 4; k++)
            acc[i][k] = __float2half2_rn(0.f);

    for (int g = 0; g < 4; g++) {
        #pragma unroll
        for (int pp = 0; pp < 4; pp++) {
            const int p = g * 4 + pp;
            const uint4 m = metap[p * 8];
            const unsigned a0 = ((m.x & 0xFFFFu) << 9) + laneoff;
            const unsigned a1 = ((m.x >> 16) << 9) + laneoff;
            const unsigned a2 = ((m.y & 0xFFFFu) << 9) + laneoff;
            const unsigned a3 = ((m.y >> 16) << 9) + laneoff;
            const int4 v0 = *(const int4*)(vb + a0);
            const int4 v1 = *(const int4*)(vb + a1);
            const int4 v2 = *(const int4*)(vb + a2);
            const int4 v3 = *(const int4*)(vb + a3);
            union { unsigned u; __half2 h2; } wz, ww;
            wz.u = m.z; ww.u = m.w;
            const __half2 ws0 = __half2half2(__low2half(wz.h2));
            const __half2 ws1 = __half2half2(__high2half(wz.h2));
            const __half2 ws2 = __half2half2(__low2half(ww.h2));
            const __half2 ws3 = __half2half2(__high2half(ww.h2));
            const __half2* p0 = (const __half2*)&v0;
            const __half2* p1 = (const __half2*)&v1;
            const __half2* p2 = (const __half2*)&v2;
            const __half2* p3 = (const __half2*)&v3;
            #pragma unroll
            for (int k = 0; k < 4; k++) {
                acc[pp][k] = __hfma2(ws0, p0[k], acc[pp][k]);
                acc[pp][k] = __hfma2(ws1, p1[k], acc[pp][k]);
                acc[pp][k] = __hfma2(ws2, p2[k], acc[pp][k]);
                acc[pp][k] = __hfma2(ws3, p3[k], acc[pp][k]);
            }
        }
    }

    uint4 o;
    unsigned* ou = &o.x;
    #pragma unroll
    for (int k = 0; k < 4; k++) {
        float2 s = {0.f, 0.f};
        #pragma unroll
        for (int i = 0; i < 4; i++) {
            const float2 f = __half22float2(acc[i][k]);
            s.x += f.x; s.y += f.y;
        }
        ou[k] = (unsigned)f2bf(s.x) | ((unsigned)f2bf(s.y) << 16);
    }
    *(uint4*)(out + (size_t)bq * 256 + h * 32 + sub * 8) = o;
}

// ---------------------------------------------------------------------------
extern "C" void kernel_launch(void* const* d_in, const int* in_sizes, int n_in,
                              void* d_out, int out_size, void* d_ws, size_t ws_size,
                              hipStream_t stream)
{
    const float* src  = (const float*)d_in[0];
    const float* pos  = (const float*)d_in[1];
    const float* Wv   = (const float*)d_in[4];
    const float* bv   = (const float*)d_in[5];
    const float* Woff = (const float*)d_in[6];
    const float* boff = (const float*)d_in[7];
    const float* Wa   = (const float*)d_in[8];
    const float* ba   = (const float*)d_in[9];
    const float* Wo   = (const float*)d_in[10];
    const float* bo   = (const float*)d_in[11];
    const float* W1   = (const float*)d_in[12];
    const float* b1   = (const float*)d_in[13];
    const float* W2   = (const float*)d_in[14];
    const float* b2   = (const float*)d_in[15];
    const float* g1   = (const float*)d_in[16];
    const float* be1  = (const float*)d_in[17];
    const float* g2   = (const float*)d_in[18];
    const float* be2  = (const float*)d_in[19];
    float* out = (float*)d_out;

    // Workspace layout (src2/tbufB round-trips eliminated by fused-LN GEMMs).
    char* wsp = (char*)d_ws;
    unsigned short* srcB = (unsigned short*)wsp; wsp += NT256 * 2;
    unsigned short* qB   = (unsigned short*)wsp; wsp += NT256 * 2;
    __half*         valB = (__half*)wsp;         wsp += NT256 * 2;
    float*          olg  = (float*)wsp;          wsp += (size_t)NTOK * 384 * 4;
    unsigned short* aoB  = (unsigned short*)wsp; wsp += NT256 * 2;
    unsigned short* xB   = (unsigned short*)wsp; wsp += NT256 * 2;
    unsigned short* h    = (unsigned short*)wsp; wsp += (size_t)NTOK * 1024 * 2;
    unsigned short* WvT  = (unsigned short*)wsp; wsp += 256 * 256 * 2;
    unsigned short* WcatT= (unsigned short*)wsp; wsp += 384 * 256 * 2;
    unsigned short* WoT  = (unsigned short*)wsp; wsp += 256 * 256 * 2;
    unsigned short* W1T  = (unsigned short*)wsp; wsp += 1024 * 256 * 2;
    unsigned short* W2T  = (unsigned short*)wsp; wsp += 256 * 1024 * 2;

    const dim3 blk(256);

    // 0. prep + all weight transposes (fused, one launch)
    prep_tr_kernel<<<dim3(5624), blk, 0, stream>>>(
        src, pos, srcB, qB, Wv, Woff, Wa, Wo, W1, W2,
        WvT, WcatT, WoT, W1T, W2T);

    // 1. value = src @ Wv + bv  (fp16 out for sampler)
    gemm_lds_kernel<256, 2, false, 2><<<dim3(2 * GYP), blk, 0, stream>>>(
        srcB, WvT, bv, bv, 1 << 30, valB, 256);
    // 2. olg = q @ [Woff|Wa] + [boff|ba]  (fp32, N=384, bias split at 256)
    gemm_lds_kernel<256, 3, false, 0><<<dim3(3 * GYP), blk, 0, stream>>>(
        qB, WcatT, boff, ba, 256, olg, 384);
    // 3. fused meta+gather -> attn_out (bf16), batch-per-XCD-pair swizzle
    msda_sample_kernel<<<dim3(NTOK / 8), blk, 0, stream>>>(valB, olg, aoB);
    // 4. xB = bf16(LN1(src + aoB @ Wo + bo))  — GEMM + residual + LN fused
    gemm_wide_ln_kernel<256, 1><<<dim3(GYR), blk, 0, stream>>>(
        aoB, WoT, bo, src, g1, be1, xB);
    // 5. h = relu(xB @ W1 + b1)
    gemm_lds_kernel<256, 8, true, 1><<<dim3(8 * GYP), blk, 0, stream>>>(
        xB, W1T, b1, b1, 1 << 30, h, 1024);
    // 6. out = LN2(xB + h @ W2 + b2)  — GEMM + residual + LN fused
    gemm_wide_ln_kernel<1024, 2><<<dim3(GYR), blk, 0, stream>>>(
        h, W2T, b2, xB, g2, be2, out);
}

// Round 9
// 238.361 us; speedup vs baseline: 1.1250x; 1.1250x over previous
//
#include <hip/hip_runtime.h>
#include <hip/hip_fp16.h>
#include <cstddef>
#include <cstdint>

// Problem constants (fixed by reference setup_inputs)
#define DMODEL 256
#define NHEAD  8
#define NLVL   4
#define NPT    4
#define DHEAD  32
#define DFFN   1024
#define SLEN   5440
#define BATCH  4
#define NTOK   (BATCH * SLEN)   // 21760 = 340*64 = 170*128
#define NT256  ((size_t)NTOK * 256)
#define GYR    170              // row-panels of 128 rows
#define GYP    176              // padded to multiple of 8 for XCD swizzle
#define LN_EPS 1e-5f

typedef __attribute__((ext_vector_type(4))) float f32x4;
typedef __attribute__((ext_vector_type(8))) short s16x8;

__device__ __forceinline__ unsigned short f2bf(float f) {
    union { float f; unsigned u; } v; v.f = f;
    unsigned u = v.u;
    u += 0x7FFFu + ((u >> 16) & 1u);   // round-to-nearest-even
    return (unsigned short)(u >> 16);
}
__device__ __forceinline__ float bf2f(unsigned short h) {
    union { unsigned u; float f; } v; v.u = ((unsigned)h) << 16;
    return v.f;
}

// async 16B global -> LDS (direct-to-shared, no VGPR round trip).
// lds dest must be wave-uniform base; HW writes lane l at base + l*16B.
__device__ __forceinline__ void g2l16(const unsigned short* g, unsigned short* l) {
    __builtin_amdgcn_global_load_lds(
        (const __attribute__((address_space(1))) unsigned int*)g,
        (__attribute__((address_space(3))) unsigned int*)l, 16, 0, 0);
}

// ---------------------------------------------------------------------------
// Fused prep + weight transposes (one launch).
// Blocks [0, 5440):   srcB = bf16(src); qB = bf16(src + pos)
// Blocks [5440, 5624): W [K][N] fp32 -> Wt [N][K] bf16 (all 6 weights;
//                      Woff & Wa into ONE concatenated WcatT [384][256]).
// ---------------------------------------------------------------------------
__global__ __launch_bounds__(256) void prep_tr_kernel(
    const float* __restrict__ src, const float* __restrict__ pos,
    unsigned short* __restrict__ srcB, unsigned short* __restrict__ qB,
    const float* __restrict__ Wv, const float* __restrict__ Woff,
    const float* __restrict__ Wa, const float* __restrict__ Wo,
    const float* __restrict__ W1, const float* __restrict__ W2,
    unsigned short* __restrict__ WvT, unsigned short* __restrict__ WcatT,
    unsigned short* __restrict__ WoT,
    unsigned short* __restrict__ W1T, unsigned short* __restrict__ W2T)
{
    if (blockIdx.x < 5440) {
        const size_t i = ((size_t)blockIdx.x * 256 + threadIdx.x) * 4;
        const float4 s = *(const float4*)(src + i);
        const float4 p = *(const float4*)(pos + i);
        ushort4 sb, qb;
        sb.x = f2bf(s.x); sb.y = f2bf(s.y); sb.z = f2bf(s.z); sb.w = f2bf(s.w);
        qb.x = f2bf(s.x + p.x); qb.y = f2bf(s.y + p.y);
        qb.z = f2bf(s.z + p.z); qb.w = f2bf(s.w + p.w);
        *(ushort4*)(srcB + i) = sb;
        *(ushort4*)(qB + i) = qb;
        return;
    }
    const int bid = blockIdx.x - 5440;
    const float* W; unsigned short* Wt; int K, N, t;
    if (bid < 16)       { W = Wv;   Wt = WvT;              K = 256;  N = 256;  t = bid; }
    else if (bid < 32)  { W = Woff; Wt = WcatT;            K = 256;  N = 256;  t = bid - 16; }
    else if (bid < 40)  { W = Wa;   Wt = WcatT + 256*256;  K = 256;  N = 128;  t = bid - 32; }
    else if (bid < 56)  { W = Wo;   Wt = WoT;              K = 256;  N = 256;  t = bid - 40; }
    else if (bid < 120) { W = W1;   Wt = W1T;              K = 256;  N = 1024; t = bid - 56; }
    else                { W = W2;   Wt = W2T;              K = 1024; N = 256;  t = bid - 120; }
    const int ntx = N >> 6;
    const int k0 = (t / ntx) * 64, n0 = (t % ntx) * 64;

    __shared__ float T[64][65];
    const int r  = threadIdx.x >> 4;
    const int c4 = (threadIdx.x & 15) * 4;
    #pragma unroll
    for (int rep = 0; rep < 4; rep++) {
        const int k = rep * 16 + r;
        const float4 v = *(const float4*)(W + (size_t)(k0 + k) * N + n0 + c4);
        T[c4 + 0][k] = v.x; T[c4 + 1][k] = v.y;
        T[c4 + 2][k] = v.z; T[c4 + 3][k] = v.w;
    }
    __syncthreads();
    #pragma unroll
    for (int rep = 0; rep < 4; rep++) {
        const int n = rep * 16 + r;
        ushort4 o;
        o.x = f2bf(T[n][c4 + 0]); o.y = f2bf(T[n][c4 + 1]);
        o.z = f2bf(T[n][c4 + 2]); o.w = f2bf(T[n][c4 + 3]);
        *(ushort4*)(Wt + (size_t)(n0 + n) * K + k0 + c4) = o;
    }
}

// ---------------------------------------------------------------------------
// 128x128 async-LDS GEMM body with counted-vmcnt pipeline (round-5
// validated). Shared by the merged value|olg kernel and FFN1.
// ---------------------------------------------------------------------------
template <int KK, bool RELU, int OM>
__device__ __forceinline__ void gemm_lds_body(
    const unsigned short* __restrict__ A,
    const unsigned short* __restrict__ Bt,
    const float* __restrict__ bias, const float* __restrict__ bias2,
    int bsplit, void* __restrict__ Cout, int N, int row0, int col0,
    unsigned short (*sA)[8192], unsigned short (*sB)[8192])
{
    const int tid  = threadIdx.x;
    const int wid  = tid >> 6;
    const int lane = tid & 63;
    const int m16  = lane & 15;
    const int q    = lane >> 4;
    const int wr   = (wid >> 1) * 64;    // wave's output row half
    const int wc   = (wid & 1) * 64;     // wave's output col half

    const int srow = lane >> 3;
    const int schk = (lane & 7) ^ srow;  // pre-swizzled global 16B chunk

    auto stage = [&](int buf, int kt) {   // 8 vmcnt ops per wave
        #pragma unroll
        for (int i = 0; i < 4; i++) {
            const int j = wid * 4 + i;           // 0..15 across the 4 waves
            const int r = j * 8 + srow;
            g2l16(A  + (size_t)(row0 + r) * KK + kt * 64 + schk * 8,
                  &sA[buf][j * 512]);
            g2l16(Bt + (size_t)(col0 + r) * KK + kt * 64 + schk * 8,
                  &sB[buf][j * 512]);
        }
    };

    f32x4 acc[4][4];
    #pragma unroll
    for (int m = 0; m < 4; m++)
        #pragma unroll
        for (int n = 0; n < 4; n++) acc[m][n] = (f32x4){0.f, 0.f, 0.f, 0.f};

    constexpr int NT = KK / 64;
    stage(0, 0);
    stage(1, 1);                         // 16 loads in flight

    #pragma unroll 1
    for (int kt = 0; kt < NT; kt++) {
        const int cur = kt & 1;

        if (kt + 1 < NT) asm volatile("s_waitcnt vmcnt(8)" ::: "memory");
        else             asm volatile("s_waitcnt vmcnt(0)" ::: "memory");
        __builtin_amdgcn_sched_barrier(0);
        __builtin_amdgcn_s_barrier();    // all waves' tile-kt loads done
        __builtin_amdgcn_sched_barrier(0);

        #pragma unroll
        for (int ks = 0; ks < 2; ks++) {
            s16x8 a[4], b[4];
            #pragma unroll
            for (int m = 0; m < 4; m++) {
                const int r  = wr + m * 16 + m16;
                const int cc = (ks * 4 + q) ^ (r & 7);   // un-swizzle on read
                a[m] = *(const s16x8*)&sA[cur][r * 64 + cc * 8];
            }
            #pragma unroll
            for (int n = 0; n < 4; n++) {
                const int r  = wc + n * 16 + m16;
                const int cc = (ks * 4 + q) ^ (r & 7);
                b[n] = *(const s16x8*)&sB[cur][r * 64 + cc * 8];
            }
            #pragma unroll
            for (int m = 0; m < 4; m++)
                #pragma unroll
                for (int n = 0; n < 4; n++)
                    acc[m][n] = __builtin_amdgcn_mfma_f32_16x16x32_bf16(
                        a[m], b[n], acc[m][n], 0, 0, 0);
        }

        asm volatile("s_waitcnt lgkmcnt(0)" ::: "memory");
        __builtin_amdgcn_sched_barrier(0);
        __builtin_amdgcn_s_barrier();
        __builtin_amdgcn_sched_barrier(0);

        if (kt + 2 < NT) stage(cur, kt + 2);   // same parity: kt+2 -> buf cur
    }

    #pragma unroll
    for (int n = 0; n < 4; n++) {
        const int col  = col0 + wc + n * 16 + m16;
        const float bc = (col < bsplit) ? bias[col] : bias2[col - bsplit];
        #pragma unroll
        for (int m = 0; m < 4; m++) {
            #pragma unroll
            for (int r = 0; r < 4; r++) {
                const int row = row0 + wr + m * 16 + q * 4 + r;
                float v = acc[m][n][r] + bc;
                if (RELU) v = fmaxf(v, 0.f);
                if (OM == 1)
                    ((unsigned short*)Cout)[(size_t)row * N + col] = f2bf(v);
                else if (OM == 2)
                    ((__half*)Cout)[(size_t)row * N + col] = __float2half(v);
                else
                    ((float*)Cout)[(size_t)row * N + col] = v;
            }
        }
    }
}

// Merged value | olg GEMM (both depend only on prep) — one launch.
// Blocks [0, 2*GYP): value = srcB @ WvT + bv  (fp16 out)
// Blocks [2*GYP, 5*GYP): olg = qB @ WcatT + [boff|ba]  (fp32, N=384)
__global__ __launch_bounds__(256, 2) void valolg_kernel(
    const unsigned short* __restrict__ srcB,
    const unsigned short* __restrict__ qB,
    const unsigned short* __restrict__ WvT,
    const unsigned short* __restrict__ WcatT,
    const float* __restrict__ bv, const float* __restrict__ boff,
    const float* __restrict__ ba,
    __half* __restrict__ valB, float* __restrict__ olg)
{
    __shared__ __align__(16) unsigned short sA[2][8192];
    __shared__ __align__(16) unsigned short sB[2][8192];

    if (blockIdx.x < 2 * GYP) {          // ---- value (NXB=2) ----
        const int lin = blockIdx.x;
        const int c8  = lin & 7;
        const int rr  = lin >> 3;
        const int bx  = rr % 2;
        const int yy  = (rr / 2) * 8 + c8;
        if (yy >= GYR) return;           // uniform per block: safe
        gemm_lds_body<256, false, 2>(srcB, WvT, bv, bv, 1 << 30,
                                     valB, 256, yy * 128, bx * 128, sA, sB);
    } else {                             // ---- olg (NXB=3) ----
        const int lin = blockIdx.x - 2 * GYP;
        const int c8  = lin & 7;
        const int rr  = lin >> 3;
        const int bx  = rr % 3;
        const int yy  = (rr / 3) * 8 + c8;
        if (yy >= GYR) return;
        gemm_lds_body<256, false, 0>(qB, WcatT, boff, ba, 256,
                                     olg, 384, yy * 128, bx * 128, sA, sB);
    }
}

// FFN1: h = relu(xB @ W1T + b1), N=1024, NXB=8.
__global__ __launch_bounds__(256, 2) void ffn1_kernel(
    const unsigned short* __restrict__ xB,
    const unsigned short* __restrict__ W1T,
    const float* __restrict__ b1, unsigned short* __restrict__ h)
{
    __shared__ __align__(16) unsigned short sA[2][8192];
    __shared__ __align__(16) unsigned short sB[2][8192];
    const int lin = blockIdx.x;
    const int c8  = lin & 7;
    const int rr  = lin >> 3;
    const int bx  = rr % 8;
    const int yy  = (rr / 8) * 8 + c8;
    if (yy >= GYR) return;
    gemm_lds_body<256, true, 1>(xB, W1T, b1, b1, 1 << 30,
                                h, 1024, yy * 128, bx * 128, sA, sB);
}

// ---------------------------------------------------------------------------
// BM=64 x BN=256 GEMM with FUSED residual+LN epilogue (round-8 math, which
// PASSED; geometry fixed per round-8 counters: grid 340 + 2 blk/CU).
// 4 waves, each owns all 64 rows x one 64-col quadrant (4x4 frags -> 16
// MFMA from 8 frag reads — same LDS-per-output as the validated 128² tile).
// LDS: dbuf A 2x8KB + B 2x32KB = 80KB -> exactly 2 blocks/CU (160KB).
// Counted vmcnt(10) = one tile's 10 loads stay in flight. LN epilogue:
// acc+bias -> fp32 lnbuf [64][260] (aliases staging, single pass), each wave
// LNs 16 full rows with the exact ln_kernel reduction order.
// LNM=1 (Wo+LN1):  resid = fp32 src,  out = bf16 xB
// LNM=2 (FFN2+LN2): resid = bf16 xB,  out = fp32 final
// ---------------------------------------------------------------------------
template <int KK, int LNM>
__global__ __launch_bounds__(256, 2) void gemm64_ln_kernel(
    const unsigned short* __restrict__ A,
    const unsigned short* __restrict__ Bt,
    const float* __restrict__ bias,
    const void* __restrict__ resid,
    const float* __restrict__ g, const float* __restrict__ be,
    void* __restrict__ outp)
{
    const int row0 = blockIdx.x * 64;    // grid = 340

    __shared__ __align__(16) unsigned short lds[40960];   // 80KB

    const int tid  = threadIdx.x;
    const int wid  = tid >> 6;
    const int lane = tid & 63;
    const int m16  = lane & 15;
    const int q    = lane >> 4;
    const int wc   = wid * 64;           // wave's col quadrant

    const int srow = lane >> 3;
    const int schk = (lane & 7) ^ srow;

    auto stage = [&](int buf, int kt) {  // 10 vmcnt ops per wave (2 A + 8 B)
        unsigned short* sAb = lds + buf * 4096;           // 8KB halves
        unsigned short* sBb = lds + 8192 + buf * 16384;   // 32KB halves
        #pragma unroll
        for (int i = 0; i < 2; i++) {
            const int j = wid * 2 + i;       // 0..7  -> A rows 0..63
            const int r = j * 8 + srow;
            g2l16(A + (size_t)(row0 + r) * KK + kt * 64 + schk * 8,
                  sAb + j * 512);
        }
        #pragma unroll
        for (int i = 0; i < 8; i++) {
            const int j = wid * 8 + i;       // 0..31 -> B rows (cols) 0..255
            const int r = j * 8 + srow;
            g2l16(Bt + (size_t)r * KK + kt * 64 + schk * 8,
                  sBb + j * 512);
        }
    };

    f32x4 acc[4][4];
    #pragma unroll
    for (int m = 0; m < 4; m++)
        #pragma unroll
        for (int n = 0; n < 4; n++) acc[m][n] = (f32x4){0.f, 0.f, 0.f, 0.f};

    constexpr int NT = KK / 64;          // 4 (Wo) or 16 (FFN2)
    stage(0, 0);
    stage(1, 1);                         // 20 loads in flight

    #pragma unroll 1
    for (int kt = 0; kt < NT; kt++) {
        const int cur = kt & 1;
        const unsigned short* sAc = lds + cur * 4096;
        const unsigned short* sBc = lds + 8192 + cur * 16384;

        if (kt + 1 < NT) asm volatile("s_waitcnt vmcnt(10)" ::: "memory");
        else             asm volatile("s_waitcnt vmcnt(0)" ::: "memory");
        __builtin_amdgcn_sched_barrier(0);
        __builtin_amdgcn_s_barrier();
        __builtin_amdgcn_sched_barrier(0);

        #pragma unroll
        for (int ks = 0; ks < 2; ks++) {
            s16x8 a[4], b[4];
            #pragma unroll
            for (int m = 0; m < 4; m++) {
                const int r  = m * 16 + m16;             // rows 0..63
                const int cc = (ks * 4 + q) ^ (r & 7);
                a[m] = *(const s16x8*)&sAc[r * 64 + cc * 8];
            }
            #pragma unroll
            for (int n = 0; n < 4; n++) {
                const int r  = wc + n * 16 + m16;        // cols 0..255
                const int cc = (ks * 4 + q) ^ (r & 7);
                b[n] = *(const s16x8*)&sBc[r * 64 + cc * 8];
            }
            #pragma unroll
            for (int m = 0; m < 4; m++)
                #pragma unroll
                for (int n = 0; n < 4; n++)
                    acc[m][n] = __builtin_amdgcn_mfma_f32_16x16x32_bf16(
                        a[m], b[n], acc[m][n], 0, 0, 0);
        }

        asm volatile("s_waitcnt lgkmcnt(0)" ::: "memory");
        __builtin_amdgcn_sched_barrier(0);
        __builtin_amdgcn_s_barrier();
        __builtin_amdgcn_sched_barrier(0);

        if (kt + 2 < NT) stage(cur, kt + 2);
    }
    // staging LDS dead (post-loop barrier) -> reuse as lnbuf
    float* lnbuf = (float*)lds;          // [64][260] fp32, 66.6KB < 80KB

    // all 4 waves deposit their col-quadrant of all 64 rows
    #pragma unroll
    for (int n = 0; n < 4; n++) {
        const int col = wc + n * 16 + m16;
        const float bc = bias[col];
        #pragma unroll
        for (int m = 0; m < 4; m++)
            #pragma unroll
            for (int r = 0; r < 4; r++)
                lnbuf[(m * 16 + q * 4 + r) * 260 + col] = acc[m][n][r] + bc;
    }
    __syncthreads();

    // each wave LNs 16 full rows (verified round-8 math)
    #pragma unroll 1
    for (int rr2 = 0; rr2 < 16; rr2++) {
        const int rl = wid * 16 + rr2;                  // local row 0..63
        const size_t grow = (size_t)row0 + rl;
        const size_t base = grow * 256 + lane * 4;

        float4 v = *(const float4*)&lnbuf[rl * 260 + lane * 4];
        if (LNM == 1) {
            const float4 rv = *(const float4*)((const float*)resid + base);
            v.x += rv.x; v.y += rv.y; v.z += rv.z; v.w += rv.w;
        } else {
            const ushort4 rb = *(const ushort4*)((const unsigned short*)resid + base);
            v.x += bf2f(rb.x); v.y += bf2f(rb.y);
            v.z += bf2f(rb.z); v.w += bf2f(rb.w);
        }

        float s  = v.x + v.y + v.z + v.w;
        float s2 = v.x * v.x + v.y * v.y + v.z * v.z + v.w * v.w;
        #pragma unroll
        for (int o = 32; o > 0; o >>= 1) {
            s  += __shfl_xor(s, o);
            s2 += __shfl_xor(s2, o);
        }
        const float mu  = s * (1.f / 256.f);
        const float var = s2 * (1.f / 256.f) - mu * mu;
        const float rn  = rsqrtf(var + LN_EPS);

        const float4 gv = *(const float4*)(g  + lane * 4);
        const float4 bv = *(const float4*)(be + lane * 4);
        float4 o4;
        o4.x = (v.x - mu) * rn * gv.x + bv.x;
        o4.y = (v.y - mu) * rn * gv.y + bv.y;
        o4.z = (v.z - mu) * rn * gv.z + bv.z;
        o4.w = (v.w - mu) * rn * gv.w + bv.w;
        if (LNM == 1) {
            ushort4 ob;
            ob.x = f2bf(o4.x); ob.y = f2bf(o4.y);
            ob.z = f2bf(o4.z); ob.w = f2bf(o4.w);
            *(ushort4*)((unsigned short*)outp + base) = ob;
        } else {
            *(float4*)((float*)outp + base) = o4;
        }
    }
}

// ---------------------------------------------------------------------------
// MSDA fused meta+gather: block = 8 tokens. (round-4 validated)
// ---------------------------------------------------------------------------
__global__ __launch_bounds__(256) void msda_sample_kernel(
    const __half* __restrict__ value, const float* __restrict__ olg,
    unsigned short* __restrict__ out)
{
    const int lin = blockIdx.x;          // 0..2719
    const int c8  = lin & 7;
    const int rr  = lin >> 3;            // 0..339
    const int b   = c8 >> 1;             // batch -> XCD pair
    const int i8  = (c8 & 1) + 2 * rr;   // 0..679: block within batch

    const int tid = threadIdx.x;
    const int sub = tid & 3;             // phase2: 16B channel group; phase1: pg
    const int h   = (tid >> 2) & 7;
    const int t8  = tid >> 5;
    const int q   = i8 * 8 + t8;         // token index within batch (< SLEN)
    const int bq  = b * SLEN + q;

    __shared__ __align__(16) uint4 smeta[8 * 16 * 8];   // [tok][p][h], 16KB

    // ---------------- phase 1: meta for (tok=t8, h, level=sub) -------------
    {
        int rem, Wq;
        if (q < 4096)      { rem = q;        Wq = 64; }
        else if (q < 5120) { rem = q - 4096; Wq = 32; }
        else if (q < 5376) { rem = q - 5120; Wq = 16; }
        else               { rem = q - 5376; Wq = 8;  }
        const int gy = rem / Wq;
        const int gx = rem - gy * Wq;
        const float ref_x = (gx + 0.5f) / (float)Wq;
        const float ref_y = (gy + 0.5f) / (float)Wq;

        const float4 lgv = *(const float4*)(olg + (size_t)bq * 384 + 256 + h * 16 + sub * 4);
        float mx = fmaxf(fmaxf(lgv.x, lgv.y), fmaxf(lgv.z, lgv.w));
        mx = fmaxf(mx, __shfl_xor(mx, 1));
        mx = fmaxf(mx, __shfl_xor(mx, 2));
        float e0 = expf(lgv.x - mx), e1 = expf(lgv.y - mx);
        float e2 = expf(lgv.z - mx), e3 = expf(lgv.w - mx);
        float s = e0 + e1 + e2 + e3;
        s += __shfl_xor(s, 1);
        s += __shfl_xor(s, 2);
        const float inv_s = 1.f / s;

        const float4 o01 = *(const float4*)(olg + (size_t)bq * 384 + h * 32 + sub * 8);
        const float4 o23 = *(const float4*)(olg + (size_t)bq * 384 + h * 32 + sub * 8 + 4);

        constexpr int LW[4] = {64, 32, 16, 8};
        constexpr int LS[4] = {0, 4096, 5120, 5376};
        const int Wl = LW[sub];
        const float fW = (float)Wl;
        const float ew[4] = {e0, e1, e2, e3};
        const float ox[4] = {o01.x, o01.z, o23.x, o23.z};
        const float oy[4] = {o01.y, o01.w, o23.y, o23.w};

        #pragma unroll
        for (int j = 0; j < 4; j++) {
            const float aw = ew[j] * inv_s;
            // mirror reference arithmetic exactly: (ref + off/W)*W - 0.5
            const float X = (ref_x + ox[j] / fW) * fW - 0.5f;
            const float Y = (ref_y + oy[j] / fW) * fW - 0.5f;
            const float x0f = floorf(X), y0f = floorf(Y);
            const float fx = X - x0f, fy = Y - y0f;
            const int x0 = (int)x0f, y0 = (int)y0f;

            unsigned idx[4]; __half hw[4];
            #pragma unroll
            for (int dy = 0; dy < 2; dy++) {
                const int yi = y0 + dy;
                const float wy = dy ? fy : (1.f - fy);
                const bool vy = (yi >= 0) && (yi < Wl);
                const int yc = min(max(yi, 0), Wl - 1);
                #pragma unroll
                for (int dx = 0; dx < 2; dx++) {
                    const int xi = x0 + dx;
                    const float wx = dx ? fx : (1.f - fx);
                    const bool vx = (xi >= 0) && (xi < Wl);
                    const int xc = min(max(xi, 0), Wl - 1);
                    const int c = dy * 2 + dx;
                    idx[c] = (unsigned)(LS[sub] + yc * Wl + xc);   // < 5440
                    hw[c] = __float2half((vx && vy) ? (aw * wx * wy) : 0.f);
                }
            }
            union { __half2 h2; unsigned u; } pk0, pk1;
            pk0.h2 = __halves2half2(hw[0], hw[1]);
            pk1.h2 = __halves2half2(hw[2], hw[3]);
            uint4 m;
            m.x = idx[0] | (idx[1] << 16);
            m.y = idx[2] | (idx[3] << 16);
            m.z = pk0.u;
            m.w = pk1.u;
            smeta[((t8 * 16) + sub * 4 + j) * 8 + h] = m;
        }
    }
    __syncthreads();

    // ---------------- phase 2: gather (validated structure) ----------------
    const char* vb = (const char*)value + (size_t)b * SLEN * 512;
    const unsigned laneoff = (unsigned)(h * 64 + sub * 16);
    const uint4* metap = &smeta[(t8 * 16) * 8 + h];    // index with p*8

    __half2 acc[4][4];
    #pragma unroll
    for (int i = 0; i < 4; i++)
        #pragma unroll
        for (int k = 0; k < 4; k++)
            acc[i][k] = __float2half2_rn(0.f);

    for (int g = 0; g < 4; g++) {
        #pragma unroll
        for (int pp = 0; pp < 4; pp++) {
            const int p = g * 4 + pp;
            const uint4 m = metap[p * 8];
            const unsigned a0 = ((m.x & 0xFFFFu) << 9) + laneoff;
            const unsigned a1 = ((m.x >> 16) << 9) + laneoff;
            const unsigned a2 = ((m.y & 0xFFFFu) << 9) + laneoff;
            const unsigned a3 = ((m.y >> 16) << 9) + laneoff;
            const int4 v0 = *(const int4*)(vb + a0);
            const int4 v1 = *(const int4*)(vb + a1);
            const int4 v2 = *(const int4*)(vb + a2);
            const int4 v3 = *(const int4*)(vb + a3);
            union { unsigned u; __half2 h2; } wz, ww;
            wz.u = m.z; ww.u = m.w;
            const __half2 ws0 = __half2half2(__low2half(wz.h2));
            const __half2 ws1 = __half2half2(__high2half(wz.h2));
            const __half2 ws2 = __half2half2(__low2half(ww.h2));
            const __half2 ws3 = __half2half2(__high2half(ww.h2));
            const __half2* p0 = (const __half2*)&v0;
            const __half2* p1 = (const __half2*)&v1;
            const __half2* p2 = (const __half2*)&v2;
            const __half2* p3 = (const __half2*)&v3;
            #pragma unroll
            for (int k = 0; k < 4; k++) {
                acc[pp][k] = __hfma2(ws0, p0[k], acc[pp][k]);
                acc[pp][k] = __hfma2(ws1, p1[k], acc[pp][k]);
                acc[pp][k] = __hfma2(ws2, p2[k], acc[pp][k]);
                acc[pp][k] = __hfma2(ws3, p3[k], acc[pp][k]);
            }
        }
    }

    uint4 o;
    unsigned* ou = &o.x;
    #pragma unroll
    for (int k = 0; k < 4; k++) {
        float2 s = {0.f, 0.f};
        #pragma unroll
        for (int i = 0; i < 4; i++) {
            const float2 f = __half22float2(acc[i][k]);
            s.x += f.x; s.y += f.y;
        }
        ou[k] = (unsigned)f2bf(s.x) | ((unsigned)f2bf(s.y) << 16);
    }
    *(uint4*)(out + (size_t)bq * 256 + h * 32 + sub * 8) = o;
}

// ---------------------------------------------------------------------------
extern "C" void kernel_launch(void* const* d_in, const int* in_sizes, int n_in,
                              void* d_out, int out_size, void* d_ws, size_t ws_size,
                              hipStream_t stream)
{
    const float* src  = (const float*)d_in[0];
    const float* pos  = (const float*)d_in[1];
    const float* Wv   = (const float*)d_in[4];
    const float* bv   = (const float*)d_in[5];
    const float* Woff = (const float*)d_in[6];
    const float* boff = (const float*)d_in[7];
    const float* Wa   = (const float*)d_in[8];
    const float* ba   = (const float*)d_in[9];
    const float* Wo   = (const float*)d_in[10];
    const float* bo   = (const float*)d_in[11];
    const float* W1   = (const float*)d_in[12];
    const float* b1   = (const float*)d_in[13];
    const float* W2   = (const float*)d_in[14];
    const float* b2   = (const float*)d_in[15];
    const float* g1   = (const float*)d_in[16];
    const float* be1  = (const float*)d_in[17];
    const float* g2   = (const float*)d_in[18];
    const float* be2  = (const float*)d_in[19];
    float* out = (float*)d_out;

    // Workspace layout (no aliasing needed; round-trips eliminated by fusion)
    char* wsp = (char*)d_ws;
    unsigned short* srcB = (unsigned short*)wsp; wsp += NT256 * 2;
    unsigned short* qB   = (unsigned short*)wsp; wsp += NT256 * 2;
    __half*         valB = (__half*)wsp;         wsp += NT256 * 2;
    float*          olg  = (float*)wsp;          wsp += (size_t)NTOK * 384 * 4;
    unsigned short* aoB  = (unsigned short*)wsp; wsp += NT256 * 2;
    unsigned short* xB   = (unsigned short*)wsp; wsp += NT256 * 2;
    unsigned short* h    = (unsigned short*)wsp; wsp += (size_t)NTOK * 1024 * 2;
    unsigned short* WvT  = (unsigned short*)wsp; wsp += 256 * 256 * 2;
    unsigned short* WcatT= (unsigned short*)wsp; wsp += 384 * 256 * 2;
    unsigned short* WoT  = (unsigned short*)wsp; wsp += 256 * 256 * 2;
    unsigned short* W1T  = (unsigned short*)wsp; wsp += 1024 * 256 * 2;
    unsigned short* W2T  = (unsigned short*)wsp; wsp += 256 * 1024 * 2;

    const dim3 blk(256);

    // 0. prep + all weight transposes
    prep_tr_kernel<<<dim3(5624), blk, 0, stream>>>(
        src, pos, srcB, qB, Wv, Woff, Wa, Wo, W1, W2,
        WvT, WcatT, WoT, W1T, W2T);

    // 1. value | olg merged (both depend only on prep)
    valolg_kernel<<<dim3(5 * GYP), blk, 0, stream>>>(
        srcB, qB, WvT, WcatT, bv, boff, ba, valB, olg);

    // 2. fused meta+gather -> attn_out (bf16)
    msda_sample_kernel<<<dim3(NTOK / 8), blk, 0, stream>>>(valB, olg, aoB);

    // 3. xB = bf16(LN1(src + aoB @ Wo + bo)) — BM=64 fused, 340 blocks
    gemm64_ln_kernel<256, 1><<<dim3(NTOK / 64), blk, 0, stream>>>(
        aoB, WoT, bo, src, g1, be1, xB);

    // 4. h = relu(xB @ W1 + b1)
    ffn1_kernel<<<dim3(8 * GYP), blk, 0, stream>>>(xB, W1T, b1, h);

    // 5. out = LN2(xB + h @ W2 + b2) — BM=64 fused, 340 blocks
    gemm64_ln_kernel<1024, 2><<<dim3(NTOK / 64), blk, 0, stream>>>(
        h, W2T, b2, xB, g2, be2, out);
}

// Round 11
// 236.417 us; speedup vs baseline: 1.1342x; 1.0082x over previous
//
#include <hip/hip_runtime.h>
#include <hip/hip_fp16.h>
#include <cstddef>
#include <cstdint>

// Problem constants (fixed by reference setup_inputs)
#define DMODEL 256
#define NHEAD  8
#define NLVL   4
#define NPT    4
#define DHEAD  32
#define DFFN   1024
#define SLEN   5440
#define BATCH  4
#define NTOK   (BATCH * SLEN)   // 21760 = 340*64 = 170*128
#define NT256  ((size_t)NTOK * 256)
#define GYR    170              // row-panels of 128 rows
#define GYP    176              // padded to multiple of 8 for XCD swizzle
#define LN_EPS 1e-5f

typedef __attribute__((ext_vector_type(4))) float f32x4;
typedef __attribute__((ext_vector_type(8))) short s16x8;

__device__ __forceinline__ unsigned short f2bf(float f) {
    union { float f; unsigned u; } v; v.f = f;
    unsigned u = v.u;
    u += 0x7FFFu + ((u >> 16) & 1u);   // round-to-nearest-even
    return (unsigned short)(u >> 16);
}
__device__ __forceinline__ float bf2f(unsigned short h) {
    union { unsigned u; float f; } v; v.u = ((unsigned)h) << 16;
    return v.f;
}

// async 16B global -> LDS (direct-to-shared, no VGPR round trip).
__device__ __forceinline__ void g2l16(const unsigned short* g, unsigned short* l) {
    __builtin_amdgcn_global_load_lds(
        (const __attribute__((address_space(1))) unsigned int*)g,
        (__attribute__((address_space(3))) unsigned int*)l, 16, 0, 0);
}

// ---------------------------------------------------------------------------
// Weight transposes only (prep is fused into valolg). 184 blocks.
// W [K][N] fp32 -> Wt [N][K] bf16; Woff & Wa into WcatT [384][256].
// ---------------------------------------------------------------------------
__global__ __launch_bounds__(256) void tr_kernel(
    const float* __restrict__ Wv, const float* __restrict__ Woff,
    const float* __restrict__ Wa, const float* __restrict__ Wo,
    const float* __restrict__ W1, const float* __restrict__ W2,
    unsigned short* __restrict__ WvT, unsigned short* __restrict__ WcatT,
    unsigned short* __restrict__ WoT,
    unsigned short* __restrict__ W1T, unsigned short* __restrict__ W2T)
{
    const int bid = blockIdx.x;
    const float* W; unsigned short* Wt; int K, N, t;
    if (bid < 16)       { W = Wv;   Wt = WvT;              K = 256;  N = 256;  t = bid; }
    else if (bid < 32)  { W = Woff; Wt = WcatT;            K = 256;  N = 256;  t = bid - 16; }
    else if (bid < 40)  { W = Wa;   Wt = WcatT + 256*256;  K = 256;  N = 128;  t = bid - 32; }
    else if (bid < 56)  { W = Wo;   Wt = WoT;              K = 256;  N = 256;  t = bid - 40; }
    else if (bid < 120) { W = W1;   Wt = W1T;              K = 256;  N = 1024; t = bid - 56; }
    else                { W = W2;   Wt = W2T;              K = 1024; N = 256;  t = bid - 120; }
    const int ntx = N >> 6;
    const int k0 = (t / ntx) * 64, n0 = (t % ntx) * 64;

    __shared__ float T[64][65];
    const int r  = threadIdx.x >> 4;
    const int c4 = (threadIdx.x & 15) * 4;
    #pragma unroll
    for (int rep = 0; rep < 4; rep++) {
        const int k = rep * 16 + r;
        const float4 v = *(const float4*)(W + (size_t)(k0 + k) * N + n0 + c4);
        T[c4 + 0][k] = v.x; T[c4 + 1][k] = v.y;
        T[c4 + 2][k] = v.z; T[c4 + 3][k] = v.w;
    }
    __syncthreads();
    #pragma unroll
    for (int rep = 0; rep < 4; rep++) {
        const int n = rep * 16 + r;
        ushort4 o;
        o.x = f2bf(T[n][c4 + 0]); o.y = f2bf(T[n][c4 + 1]);
        o.z = f2bf(T[n][c4 + 2]); o.w = f2bf(T[n][c4 + 3]);
        *(ushort4*)(Wt + (size_t)(n0 + n) * K + k0 + c4) = o;
    }
}

// ---------------------------------------------------------------------------
// value|olg GEMM with FUSED on-the-fly prep: A is reg-staged from fp32
// src (+pos for olg) and converted with the same f2bf as the old prep,
// written into the IDENTICAL swizzled LDS layout g2l16 produced (lane l at
// base + l*16B, global chunk (l&7)^(l>>3)). B stays async g2l16.
// Single-buffer 2-barrier loop (dbuf/counted-vmcnt were ~null at K=256,
// rounds 4-5). Eliminates the prep kernel and srcB/qB round-trips.
// ASRC: 0 = src (value A), 1 = src+pos (query A).
// ---------------------------------------------------------------------------
template <int ASRC, int OM>
__device__ __forceinline__ void gemm_prep_body(
    const float* __restrict__ srcf, const float* __restrict__ posf,
    const unsigned short* __restrict__ Bt,
    const float* __restrict__ bias, const float* __restrict__ bias2,
    int bsplit, void* __restrict__ Cout, int N, int row0, int col0,
    unsigned short* sA, unsigned short* sB)
{
    const int tid  = threadIdx.x;
    const int wid  = tid >> 6;
    const int lane = tid & 63;
    const int m16  = lane & 15;
    const int q    = lane >> 4;
    const int wr   = (wid >> 1) * 64;    // wave's output row half
    const int wc   = (wid & 1) * 64;     // wave's output col half
    const int srow = lane >> 3;
    const int schk = (lane & 7) ^ srow;  // pre-swizzled global 16B chunk

    f32x4 acc[4][4];
    #pragma unroll
    for (int m = 0; m < 4; m++)
        #pragma unroll
        for (int n = 0; n < 4; n++) acc[m][n] = (f32x4){0.f, 0.f, 0.f, 0.f};

    #pragma unroll 1
    for (int kt = 0; kt < 4; kt++) {     // KK = 256 fixed
        #pragma unroll
        for (int i = 0; i < 4; i++) {
            const int j = wid * 4 + i;           // 0..15 across the 4 waves
            const int r = j * 8 + srow;
            // ---- A: fp32 load -> f2bf -> ds_write (same layout as g2l16) --
            const size_t go = (size_t)(row0 + r) * 256 + kt * 64 + schk * 8;
            const float4 f0 = *(const float4*)(srcf + go);
            const float4 f1 = *(const float4*)(srcf + go + 4);
            s16x8 av;
            if (ASRC) {
                const float4 p0 = *(const float4*)(posf + go);
                const float4 p1 = *(const float4*)(posf + go + 4);
                av[0] = (short)f2bf(f0.x + p0.x); av[1] = (short)f2bf(f0.y + p0.y);
                av[2] = (short)f2bf(f0.z + p0.z); av[3] = (short)f2bf(f0.w + p0.w);
                av[4] = (short)f2bf(f1.x + p1.x); av[5] = (short)f2bf(f1.y + p1.y);
                av[6] = (short)f2bf(f1.z + p1.z); av[7] = (short)f2bf(f1.w + p1.w);
            } else {
                av[0] = (short)f2bf(f0.x); av[1] = (short)f2bf(f0.y);
                av[2] = (short)f2bf(f0.z); av[3] = (short)f2bf(f0.w);
                av[4] = (short)f2bf(f1.x); av[5] = (short)f2bf(f1.y);
                av[6] = (short)f2bf(f1.z); av[7] = (short)f2bf(f1.w);
            }
            *(s16x8*)&sA[j * 512 + lane * 8] = av;   // lane*16B, like g2l16
            // ---- B: async direct-to-LDS ----
            g2l16(Bt + (size_t)(col0 + r) * 256 + kt * 64 + schk * 8,
                  sB + j * 512);
        }
        __syncthreads();                 // drains vmcnt(0)+lgkmcnt: tile ready

        #pragma unroll
        for (int ks = 0; ks < 2; ks++) {
            s16x8 a[4], b[4];
            #pragma unroll
            for (int m = 0; m < 4; m++) {
                const int r  = wr + m * 16 + m16;
                const int cc = (ks * 4 + q) ^ (r & 7);   // un-swizzle on read
                a[m] = *(const s16x8*)&sA[r * 64 + cc * 8];
            }
            #pragma unroll
            for (int n = 0; n < 4; n++) {
                const int r  = wc + n * 16 + m16;
                const int cc = (ks * 4 + q) ^ (r & 7);
                b[n] = *(const s16x8*)&sB[r * 64 + cc * 8];
            }
            #pragma unroll
            for (int m = 0; m < 4; m++)
                #pragma unroll
                for (int n = 0; n < 4; n++)
                    acc[m][n] = __builtin_amdgcn_mfma_f32_16x16x32_bf16(
                        a[m], b[n], acc[m][n], 0, 0, 0);
        }
        __syncthreads();                 // reads done; safe to restage
    }

    // epilogue: D layout col=lane&15, row=(lane>>4)*4+reg (m89/m91-verified)
    #pragma unroll
    for (int n = 0; n < 4; n++) {
        const int col  = col0 + wc + n * 16 + m16;
        const float bc = (col < bsplit) ? bias[col] : bias2[col - bsplit];
        #pragma unroll
        for (int m = 0; m < 4; m++) {
            #pragma unroll
            for (int r = 0; r < 4; r++) {
                const int row = row0 + wr + m * 16 + q * 4 + r;
                float v = acc[m][n][r] + bc;
                if (OM == 2)
                    ((__half*)Cout)[(size_t)row * N + col] = __float2half(v);
                else
                    ((float*)Cout)[(size_t)row * N + col] = v;
            }
        }
    }
}

// Merged value | olg GEMM with fused prep — one launch.
// Blocks [0, 2*GYP): value = bf16(src) @ WvT + bv  (fp16 out)
// Blocks [2*GYP, 5*GYP): olg = bf16(src+pos) @ WcatT + [boff|ba] (fp32, N=384)
__global__ __launch_bounds__(256, 2) void valolg_kernel(
    const float* __restrict__ src, const float* __restrict__ pos,
    const unsigned short* __restrict__ WvT,
    const unsigned short* __restrict__ WcatT,
    const float* __restrict__ bv, const float* __restrict__ boff,
    const float* __restrict__ ba,
    __half* __restrict__ valB, float* __restrict__ olg)
{
    __shared__ __align__(16) unsigned short sA[8192];
    __shared__ __align__(16) unsigned short sB[8192];

    if (blockIdx.x < 2 * GYP) {          // ---- value (NXB=2) ----
        const int lin = blockIdx.x;
        const int c8  = lin & 7;
        const int rr  = lin >> 3;
        const int bx  = rr % 2;
        const int yy  = (rr / 2) * 8 + c8;
        if (yy >= GYR) return;           // uniform per block: safe
        gemm_prep_body<0, 2>(src, pos, WvT, bv, bv, 1 << 30,
                             valB, 256, yy * 128, bx * 128, sA, sB);
    } else {                             // ---- olg (NXB=3) ----
        const int lin = blockIdx.x - 2 * GYP;
        const int c8  = lin & 7;
        const int rr  = lin >> 3;
        const int bx  = rr % 3;
        const int yy  = (rr / 3) * 8 + c8;
        if (yy >= GYR) return;
        gemm_prep_body<1, 0>(src, pos, WcatT, boff, ba, 256,
                             olg, 384, yy * 128, bx * 128, sA, sB);
    }
}

// ---------------------------------------------------------------------------
// 128x128 async-LDS GEMM body with counted-vmcnt pipeline (round-5
// validated). Used by FFN1.
// ---------------------------------------------------------------------------
template <int KK, bool RELU, int OM>
__device__ __forceinline__ void gemm_lds_body(
    const unsigned short* __restrict__ A,
    const unsigned short* __restrict__ Bt,
    const float* __restrict__ bias, const float* __restrict__ bias2,
    int bsplit, void* __restrict__ Cout, int N, int row0, int col0,
    unsigned short (*sA)[8192], unsigned short (*sB)[8192])
{
    const int tid  = threadIdx.x;
    const int wid  = tid >> 6;
    const int lane = tid & 63;
    const int m16  = lane & 15;
    const int q    = lane >> 4;
    const int wr   = (wid >> 1) * 64;    // wave's output row half
    const int wc   = (wid & 1) * 64;     // wave's output col half

    const int srow = lane >> 3;
    const int schk = (lane & 7) ^ srow;

    auto stage = [&](int buf, int kt) {   // 8 vmcnt ops per wave
        #pragma unroll
        for (int i = 0; i < 4; i++) {
            const int j = wid * 4 + i;           // 0..15 across the 4 waves
            const int r = j * 8 + srow;
            g2l16(A  + (size_t)(row0 + r) * KK + kt * 64 + schk * 8,
                  &sA[buf][j * 512]);
            g2l16(Bt + (size_t)(col0 + r) * KK + kt * 64 + schk * 8,
                  &sB[buf][j * 512]);
        }
    };

    f32x4 acc[4][4];
    #pragma unroll
    for (int m = 0; m < 4; m++)
        #pragma unroll
        for (int n = 0; n < 4; n++) acc[m][n] = (f32x4){0.f, 0.f, 0.f, 0.f};

    constexpr int NT = KK / 64;
    stage(0, 0);
    stage(1, 1);                         // 16 loads in flight

    #pragma unroll 1
    for (int kt = 0; kt < NT; kt++) {
        const int cur = kt & 1;

        if (kt + 1 < NT) asm volatile("s_waitcnt vmcnt(8)" ::: "memory");
        else             asm volatile("s_waitcnt vmcnt(0)" ::: "memory");
        __builtin_amdgcn_sched_barrier(0);
        __builtin_amdgcn_s_barrier();    // all waves' tile-kt loads done
        __builtin_amdgcn_sched_barrier(0);

        #pragma unroll
        for (int ks = 0; ks < 2; ks++) {
            s16x8 a[4], b[4];
            #pragma unroll
            for (int m = 0; m < 4; m++) {
                const int r  = wr + m * 16 + m16;
                const int cc = (ks * 4 + q) ^ (r & 7);   // un-swizzle on read
                a[m] = *(const s16x8*)&sA[cur][r * 64 + cc * 8];
            }
            #pragma unroll
            for (int n = 0; n < 4; n++) {
                const int r  = wc + n * 16 + m16;
                const int cc = (ks * 4 + q) ^ (r & 7);
                b[n] = *(const s16x8*)&sB[cur][r * 64 + cc * 8];
            }
            #pragma unroll
            for (int m = 0; m < 4; m++)
                #pragma unroll
                for (int n = 0; n < 4; n++)
                    acc[m][n] = __builtin_amdgcn_mfma_f32_16x16x32_bf16(
                        a[m], b[n], acc[m][n], 0, 0, 0);
        }

        asm volatile("s_waitcnt lgkmcnt(0)" ::: "memory");
        __builtin_amdgcn_sched_barrier(0);
        __builtin_amdgcn_s_barrier();
        __builtin_amdgcn_sched_barrier(0);

        if (kt + 2 < NT) stage(cur, kt + 2);   // same parity: kt+2 -> buf cur
    }

    #pragma unroll
    for (int n = 0; n < 4; n++) {
        const int col  = col0 + wc + n * 16 + m16;
        const float bc = (col < bsplit) ? bias[col] : bias2[col - bsplit];
        #pragma unroll
        for (int m = 0; m < 4; m++) {
            #pragma unroll
            for (int r = 0; r < 4; r++) {
                const int row = row0 + wr + m * 16 + q * 4 + r;
                float v = acc[m][n][r] + bc;
                if (RELU) v = fmaxf(v, 0.f);
                if (OM == 1)
                    ((unsigned short*)Cout)[(size_t)row * N + col] = f2bf(v);
                else if (OM == 2)
                    ((__half*)Cout)[(size_t)row * N + col] = __float2half(v);
                else
                    ((float*)Cout)[(size_t)row * N + col] = v;
            }
        }
    }
}

// FFN1: h = relu(xB @ W1T + b1), N=1024, NXB=8.
__global__ __launch_bounds__(256, 2) void ffn1_kernel(
    const unsigned short* __restrict__ xB,
    const unsigned short* __restrict__ W1T,
    const float* __restrict__ b1, unsigned short* __restrict__ h)
{
    __shared__ __align__(16) unsigned short sA[2][8192];
    __shared__ __align__(16) unsigned short sB[2][8192];
    const int lin = blockIdx.x;
    const int c8  = lin & 7;
    const int rr  = lin >> 3;
    const int bx  = rr % 8;
    const int yy  = (rr / 8) * 8 + c8;
    if (yy >= GYR) return;
    gemm_lds_body<256, true, 1>(xB, W1T, b1, b1, 1 << 30,
                                h, 1024, yy * 128, bx * 128, sA, sB);
}

// ---------------------------------------------------------------------------
// BM=64 x BN=256 GEMM with FUSED residual+LN epilogue (round-9 validated:
// 238.4us run, absmax 0.03125). grid 340, 2 blk/CU (80KB LDS).
// LNM=1 (Wo+LN1):  resid = fp32 src,  out = bf16 xB
// LNM=2 (FFN2+LN2): resid = bf16 xB,  out = fp32 final
// ---------------------------------------------------------------------------
template <int KK, int LNM>
__global__ __launch_bounds__(256, 2) void gemm64_ln_kernel(
    const unsigned short* __restrict__ A,
    const unsigned short* __restrict__ Bt,
    const float* __restrict__ bias,
    const void* __restrict__ resid,
    const float* __restrict__ g, const float* __restrict__ be,
    void* __restrict__ outp)
{
    const int row0 = blockIdx.x * 64;    // grid = 340

    __shared__ __align__(16) unsigned short lds[40960];   // 80KB

    const int tid  = threadIdx.x;
    const int wid  = tid >> 6;
    const int lane = tid & 63;
    const int m16  = lane & 15;
    const int q    = lane >> 4;
    const int wc   = wid * 64;           // wave's col quadrant

    const int srow = lane >> 3;
    const int schk = (lane & 7) ^ srow;

    auto stage = [&](int buf, int kt) {  // 10 vmcnt ops per wave (2 A + 8 B)
        unsigned short* sAb = lds + buf * 4096;           // 8KB halves
        unsigned short* sBb = lds + 8192 + buf * 16384;   // 32KB halves
        #pragma unroll
        for (int i = 0; i < 2; i++) {
            const int j = wid * 2 + i;       // 0..7  -> A rows 0..63
            const int r = j * 8 + srow;
            g2l16(A + (size_t)(row0 + r) * KK + kt * 64 + schk * 8,
                  sAb + j * 512);
        }
        #pragma unroll
        for (int i = 0; i < 8; i++) {
            const int j = wid * 8 + i;       // 0..31 -> B rows (cols) 0..255
            const int r = j * 8 + srow;
            g2l16(Bt + (size_t)r * KK + kt * 64 + schk * 8,
                  sBb + j * 512);
        }
    };

    f32x4 acc[4][4];
    #pragma unroll
    for (int m = 0; m < 4; m++)
        #pragma unroll
        for (int n = 0; n < 4; n++) acc[m][n] = (f32x4){0.f, 0.f, 0.f, 0.f};

    constexpr int NT = KK / 64;          // 4 (Wo) or 16 (FFN2)
    stage(0, 0);
    stage(1, 1);                         // 20 loads in flight

    #pragma unroll 1
    for (int kt = 0; kt < NT; kt++) {
        const int cur = kt & 1;
        const unsigned short* sAc = lds + cur * 4096;
        const unsigned short* sBc = lds + 8192 + cur * 16384;

        if (kt + 1 < NT) asm volatile("s_waitcnt vmcnt(10)" ::: "memory");
        else             asm volatile("s_waitcnt vmcnt(0)" ::: "memory");
        __builtin_amdgcn_sched_barrier(0);
        __builtin_amdgcn_s_barrier();
        __builtin_amdgcn_sched_barrier(0);

        #pragma unroll
        for (int ks = 0; ks < 2; ks++) {
            s16x8 a[4], b[4];
            #pragma unroll
            for (int m = 0; m < 4; m++) {
                const int r  = m * 16 + m16;             // rows 0..63
                const int cc = (ks * 4 + q) ^ (r & 7);
                a[m] = *(const s16x8*)&sAc[r * 64 + cc * 8];
            }
            #pragma unroll
            for (int n = 0; n < 4; n++) {
                const int r  = wc + n * 16 + m16;        // cols 0..255
                const int cc = (ks * 4 + q) ^ (r & 7);
                b[n] = *(const s16x8*)&sBc[r * 64 + cc * 8];
            }
            #pragma unroll
            for (int m = 0; m < 4; m++)
                #pragma unroll
                for (int n = 0; n < 4; n++)
                    acc[m][n] = __builtin_amdgcn_mfma_f32_16x16x32_bf16(
                        a[m], b[n], acc[m][n], 0, 0, 0);
        }

        asm volatile("s_waitcnt lgkmcnt(0)" ::: "memory");
        __builtin_amdgcn_sched_barrier(0);
        __builtin_amdgcn_s_barrier();
        __builtin_amdgcn_sched_barrier(0);

        if (kt + 2 < NT) stage(cur, kt + 2);
    }
    // staging LDS dead (post-loop barrier) -> reuse as lnbuf
    float* lnbuf = (float*)lds;          // [64][260] fp32, 66.6KB < 80KB

    // all 4 waves deposit their col-quadrant of all 64 rows
    #pragma unroll
    for (int n = 0; n < 4; n++) {
        const int col = wc + n * 16 + m16;
        const float bc = bias[col];
        #pragma unroll
        for (int m = 0; m < 4; m++)
            #pragma unroll
            for (int r = 0; r < 4; r++)
                lnbuf[(m * 16 + q * 4 + r) * 260 + col] = acc[m][n][r] + bc;
    }
    __syncthreads();

    // each wave LNs 16 full rows (round-8/9 verified math)
    #pragma unroll 1
    for (int rr2 = 0; rr2 < 16; rr2++) {
        const int rl = wid * 16 + rr2;                  // local row 0..63
        const size_t grow = (size_t)row0 + rl;
        const size_t base = grow * 256 + lane * 4;

        float4 v = *(const float4*)&lnbuf[rl * 260 + lane * 4];
        if (LNM == 1) {
            const float4 rv = *(const float4*)((const float*)resid + base);
            v.x += rv.x; v.y += rv.y; v.z += rv.z; v.w += rv.w;
        } else {
            const ushort4 rb = *(const ushort4*)((const unsigned short*)resid + base);
            v.x += bf2f(rb.x); v.y += bf2f(rb.y);
            v.z += bf2f(rb.z); v.w += bf2f(rb.w);
        }

        float s  = v.x + v.y + v.z + v.w;
        float s2 = v.x * v.x + v.y * v.y + v.z * v.z + v.w * v.w;
        #pragma unroll
        for (int o = 32; o > 0; o >>= 1) {
            s  += __shfl_xor(s, o);
            s2 += __shfl_xor(s2, o);
        }
        const float mu  = s * (1.f / 256.f);
        const float var = s2 * (1.f / 256.f) - mu * mu;
        const float rn  = rsqrtf(var + LN_EPS);

        const float4 gv = *(const float4*)(g  + lane * 4);
        const float4 bv = *(const float4*)(be + lane * 4);
        float4 o4;
        o4.x = (v.x - mu) * rn * gv.x + bv.x;
        o4.y = (v.y - mu) * rn * gv.y + bv.y;
        o4.z = (v.z - mu) * rn * gv.z + bv.z;
        o4.w = (v.w - mu) * rn * gv.w + bv.w;
        if (LNM == 1) {
            ushort4 ob;
            ob.x = f2bf(o4.x); ob.y = f2bf(o4.y);
            ob.z = f2bf(o4.z); ob.w = f2bf(o4.w);
            *(ushort4*)((unsigned short*)outp + base) = ob;
        } else {
            *(float4*)((float*)outp + base) = o4;
        }
    }
}

// ---------------------------------------------------------------------------
// MSDA fused meta+gather: block = 8 tokens. (round-4/9 validated)
// ---------------------------------------------------------------------------
__global__ __launch_bounds__(256) void msda_sample_kernel(
    const __half* __restrict__ value, const float* __restrict__ olg,
    unsigned short* __restrict__ out)
{
    const int lin = blockIdx.x;          // 0..2719
    const int c8  = lin & 7;
    const int rr  = lin >> 3;            // 0..339
    const int b   = c8 >> 1;             // batch -> XCD pair
    const int i8  = (c8 & 1) + 2 * rr;   // 0..679: block within batch

    const int tid = threadIdx.x;
    const int sub = tid & 3;             // phase2: 16B channel group; phase1: pg
    const int h   = (tid >> 2) & 7;
    const int t8  = tid >> 5;
    const int q   = i8 * 8 + t8;         // token index within batch (< SLEN)
    const int bq  = b * SLEN + q;

    __shared__ __align__(16) uint4 smeta[8 * 16 * 8];   // [tok][p][h], 16KB

    // ---------------- phase 1: meta for (tok=t8, h, level=sub) -------------
    {
        int rem, Wq;
        if (q < 4096)      { rem = q;        Wq = 64; }
        else if (q < 5120) { rem = q - 4096; Wq = 32; }
        else if (q < 5376) { rem = q - 5120; Wq = 16; }
        else               { rem = q - 5376; Wq = 8;  }
        const int gy = rem / Wq;
        const int gx = rem - gy * Wq;
        const float ref_x = (gx + 0.5f) / (float)Wq;
        const float ref_y = (gy + 0.5f) / (float)Wq;

        const float4 lgv = *(const float4*)(olg + (size_t)bq * 384 + 256 + h * 16 + sub * 4);
        float mx = fmaxf(fmaxf(lgv.x, lgv.y), fmaxf(lgv.z, lgv.w));
        mx = fmaxf(mx, __shfl_xor(mx, 1));
        mx = fmaxf(mx, __shfl_xor(mx, 2));
        float e0 = expf(lgv.x - mx), e1 = expf(lgv.y - mx);
        float e2 = expf(lgv.z - mx), e3 = expf(lgv.w - mx);
        float s = e0 + e1 + e2 + e3;
        s += __shfl_xor(s, 1);
        s += __shfl_xor(s, 2);
        const float inv_s = 1.f / s;

        const float4 o01 = *(const float4*)(olg + (size_t)bq * 384 + h * 32 + sub * 8);
        const float4 o23 = *(const float4*)(olg + (size_t)bq * 384 + h * 32 + sub * 8 + 4);

        constexpr int LW[4] = {64, 32, 16, 8};
        constexpr int LS[4] = {0, 4096, 5120, 5376};
        const int Wl = LW[sub];
        const float fW = (float)Wl;
        const float ew[4] = {e0, e1, e2, e3};
        const float ox[4] = {o01.x, o01.z, o23.x, o23.z};
        const float oy[4] = {o01.y, o01.w, o23.y, o23.w};

        #pragma unroll
        for (int j = 0; j < 4; j++) {
            const float aw = ew[j] * inv_s;
            // mirror reference arithmetic exactly: (ref + off/W)*W - 0.5
            const float X = (ref_x + ox[j] / fW) * fW - 0.5f;
            const float Y = (ref_y + oy[j] / fW) * fW - 0.5f;
            const float x0f = floorf(X), y0f = floorf(Y);
            const float fx = X - x0f, fy = Y - y0f;
            const int x0 = (int)x0f, y0 = (int)y0f;

            unsigned idx[4]; __half hw[4];
            #pragma unroll
            for (int dy = 0; dy < 2; dy++) {
                const int yi = y0 + dy;
                const float wy = dy ? fy : (1.f - fy);
                const bool vy = (yi >= 0) && (yi < Wl);
                const int yc = min(max(yi, 0), Wl - 1);
                #pragma unroll
                for (int dx = 0; dx < 2; dx++) {
                    const int xi = x0 + dx;
                    const float wx = dx ? fx : (1.f - fx);
                    const bool vx = (xi >= 0) && (xi < Wl);
                    const int xc = min(max(xi, 0), Wl - 1);
                    const int c = dy * 2 + dx;
                    idx[c] = (unsigned)(LS[sub] + yc * Wl + xc);   // < 5440
                    hw[c] = __float2half((vx && vy) ? (aw * wx * wy) : 0.f);
                }
            }
            union { __half2 h2; unsigned u; } pk0, pk1;
            pk0.h2 = __halves2half2(hw[0], hw[1]);
            pk1.h2 = __halves2half2(hw[2], hw[3]);
            uint4 m;
            m.x = idx[0] | (idx[1] << 16);
            m.y = idx[2] | (idx[3] << 16);
            m.z = pk0.u;
            m.w = pk1.u;
            smeta[((t8 * 16) + sub * 4 + j) * 8 + h] = m;
        }
    }
    __syncthreads();

    // ---------------- phase 2: gather (validated structure) ----------------
    const char* vb = (const char*)value + (size_t)b * SLEN * 512;
    const unsigned laneoff = (unsigned)(h * 64 + sub * 16);
    const uint4* metap = &smeta[(t8 * 16) * 8 + h];    // index with p*8

    __half2 acc[4][4];
    #pragma unroll
    for (int i = 0; i < 4; i++)
        #pragma unroll
        for (int k = 0; k < 4; k++)
            acc[i][k] = __float2half2_rn(0.f);

    for (int g = 0; g < 4; g++) {
        #pragma unroll
        for (int pp = 0; pp < 4; pp++) {
            const int p = g * 4 + pp;
            const uint4 m = metap[p * 8];
            const unsigned a0 = ((m.x & 0xFFFFu) << 9) + laneoff;
            const unsigned a1 = ((m.x >> 16) << 9) + laneoff;
            const unsigned a2 = ((m.y & 0xFFFFu) << 9) + laneoff;
            const unsigned a3 = ((m.y >> 16) << 9) + laneoff;
            const int4 v0 = *(const int4*)(vb + a0);
            const int4 v1 = *(const int4*)(vb + a1);
            const int4 v2 = *(const int4*)(vb + a2);
            const int4 v3 = *(const int4*)(vb + a3);
            union { unsigned u; __half2 h2; } wz, ww;
            wz.u = m.z; ww.u = m.w;
            const __half2 ws0 = __half2half2(__low2half(wz.h2));
            const __half2 ws1 = __half2half2(__high2half(wz.h2));
            const __half2 ws2 = __half2half2(__low2half(ww.h2));
            const __half2 ws3 = __half2half2(__high2half(ww.h2));
            const __half2* p0 = (const __half2*)&v0;
            const __half2* p1 = (const __half2*)&v1;
            const __half2* p2 = (const __half2*)&v2;
            const __half2* p3 = (const __half2*)&v3;
            #pragma unroll
            for (int k = 0; k < 4; k++) {
                acc[pp][k] = __hfma2(ws0, p0[k], acc[pp][k]);
                acc[pp][k] = __hfma2(ws1, p1[k], acc[pp][k]);
                acc[pp][k] = __hfma2(ws2, p2[k], acc[pp][k]);
                acc[pp][k] = __hfma2(ws3, p3[k], acc[pp][k]);
            }
        }
    }

    uint4 o;
    unsigned* ou = &o.x;
    #pragma unroll
    for (int k = 0; k < 4; k++) {
        float2 s = {0.f, 0.f};
        #pragma unroll
        for (int i = 0; i < 4; i++) {
            const float2 f = __half22float2(acc[i][k]);
            s.x += f.x; s.y += f.y;
        }
        ou[k] = (unsigned)f2bf(s.x) | ((unsigned)f2bf(s.y) << 16);
    }
    *(uint4*)(out + (size_t)bq * 256 + h * 32 + sub * 8) = o;
}

// ---------------------------------------------------------------------------
extern "C" void kernel_launch(void* const* d_in, const int* in_sizes, int n_in,
                              void* d_out, int out_size, void* d_ws, size_t ws_size,
                              hipStream_t stream)
{
    const float* src  = (const float*)d_in[0];
    const float* pos  = (const float*)d_in[1];
    const float* Wv   = (const float*)d_in[4];
    const float* bv   = (const float*)d_in[5];
    const float* Woff = (const float*)d_in[6];
    const float* boff = (const float*)d_in[7];
    const float* Wa   = (const float*)d_in[8];
    const float* ba   = (const float*)d_in[9];
    const float* Wo   = (const float*)d_in[10];
    const float* bo   = (const float*)d_in[11];
    const float* W1   = (const float*)d_in[12];
    const float* b1   = (const float*)d_in[13];
    const float* W2   = (const float*)d_in[14];
    const float* b2   = (const float*)d_in[15];
    const float* g1   = (const float*)d_in[16];
    const float* be1  = (const float*)d_in[17];
    const float* g2   = (const float*)d_in[18];
    const float* be2  = (const float*)d_in[19];
    float* out = (float*)d_out;

    // Workspace layout (srcB/qB eliminated by fused prep).
    char* wsp = (char*)d_ws;
    __half*         valB = (__half*)wsp;         wsp += NT256 * 2;
    float*          olg  = (float*)wsp;          wsp += (size_t)NTOK * 384 * 4;
    unsigned short* aoB  = (unsigned short*)wsp; wsp += NT256 * 2;
    unsigned short* xB   = (unsigned short*)wsp; wsp += NT256 * 2;
    unsigned short* h    = (unsigned short*)wsp; wsp += (size_t)NTOK * 1024 * 2;
    unsigned short* WvT  = (unsigned short*)wsp; wsp += 256 * 256 * 2;
    unsigned short* WcatT= (unsigned short*)wsp; wsp += 384 * 256 * 2;
    unsigned short* WoT  = (unsigned short*)wsp; wsp += 256 * 256 * 2;
    unsigned short* W1T  = (unsigned short*)wsp; wsp += 1024 * 256 * 2;
    unsigned short* W2T  = (unsigned short*)wsp; wsp += 256 * 1024 * 2;

    const dim3 blk(256);

    // 0. weight transposes only (prep fused into valolg)
    tr_kernel<<<dim3(184), blk, 0, stream>>>(
        Wv, Woff, Wa, Wo, W1, W2, WvT, WcatT, WoT, W1T, W2T);

    // 1. value | olg merged with inline prep (fp32 -> bf16 during staging)
    valolg_kernel<<<dim3(5 * GYP), blk, 0, stream>>>(
        src, pos, WvT, WcatT, bv, boff, ba, valB, olg);

    // 2. fused meta+gather -> attn_out (bf16)
    msda_sample_kernel<<<dim3(NTOK / 8), blk, 0, stream>>>(valB, olg, aoB);

    // 3. xB = bf16(LN1(src + aoB @ Wo + bo)) — BM=64 fused, 340 blocks
    gemm64_ln_kernel<256, 1><<<dim3(NTOK / 64), blk, 0, stream>>>(
        aoB, WoT, bo, src, g1, be1, xB);

    // 4. h = relu(xB @ W1 + b1)
    ffn1_kernel<<<dim3(8 * GYP), blk, 0, stream>>>(xB, W1T, b1, h);

    // 5. out = LN2(xB + h @ W2 + b2) — BM=64 fused, 340 blocks
    gemm64_ln_kernel<1024, 2><<<dim3(NTOK / 64), blk, 0, stream>>>(
        h, W2T, b2, xB, g2, be2, out);
}